// Round 7
// baseline (1900.411 us; speedup 1.0000x reference)
//
#include <hip/hip_runtime.h>

typedef __bf16 bf16_t;
typedef bf16_t bf16x8 __attribute__((ext_vector_type(8)));
typedef float f32x4 __attribute__((ext_vector_type(4)));

#define NSEQ 2048
#define EMB 512
#define HEADS 8
#define HD 64
#define BATCH 4
#define LOG2E 1.4426950408889634f

#define MFMA16(a, b, c) __builtin_amdgcn_mfma_f32_16x16x32_bf16(a, b, c, 0, 0, 0)

// Fragment-major layouts (frag = 64 lanes x 8 bf16, contiguous 1 KB):
//   Kf[((bh*128 + kt16)*2 + kk)*512 + lane*8 + j]
//       = K[bh][key = kt16*16 + (lane&15)][d = kk*32 + (lane>>4)*8 + j]
//   (doubles as both the A-frag of K-tiles and the B-frag of Q^T-tiles)
//   Vf[((bh*64 + kt32)*4 + dt)*512 + lane*8 + j]
//       = V[bh][key = kt32*32 + (lane>>4)*8 + j][d = dt*16 + (lane&15)]

// ---------------------------------------------------------------------------
// Fused K/V projection GEMM with inline fp32->bf16 convert (R4-validated
// core): C[8192,1024] = x @ [Wk;Wv]^T + [bk;bv]. 128x128 tile, BK=64,
// register-prefetch pipeline. Epilogue now emits FRAGMENT-MAJOR Kf/Vf.
// ---------------------------------------------------------------------------
__global__ __launch_bounds__(256, 2) void proj_kernel(
    const float* __restrict__ x,
    const float* __restrict__ Wk, const float* __restrict__ bk,
    const float* __restrict__ Wv, const float* __restrict__ bv,
    bf16_t* __restrict__ Kf, bf16_t* __restrict__ Vf)
{
  __shared__ union {
    struct {
      __align__(16) bf16_t A[2][128][40];   // [kk-half][row][32 el + pad]
      __align__(16) bf16_t B[2][128][40];
    } s;
    __align__(16) bf16_t T[128][136];       // epilogue relayout buffer
  } u;

  const int t    = threadIdx.x;
  const int w    = t >> 6;
  const int lane = t & 63;
  const int quad = lane >> 4;
  const int l15  = lane & 15;
  const int wr   = w >> 1, wc = w & 1;
  const int m0   = blockIdx.x * 128;
  const int n0   = blockIdx.y * 128;        // stacked feature base 0..896
  const int zz   = (blockIdx.y >= 4);       // 0: K-features, 1: V-features
  const float* __restrict__ W = zz ? Wv : Wk;
  const int nW = n0 - zz * 512;             // row base within W

  const int sr = t >> 3;        // staging row 0..31 (x4 groups)
  const int sj = t & 7;         // 8-el chunk 0..7 within 64-el k slab
  const int sb = sj >> 2, sc = (sj & 3) * 8;

  float4 pa[4][2], pb[4][2];
  auto prefetch = [&](int k0) {
#pragma unroll
    for (int i = 0; i < 4; ++i) {
      const float* xa = x + (size_t)(m0 + sr + i * 32) * EMB + k0 + sj * 8;
      const float* wa = W + (size_t)(nW + sr + i * 32) * EMB + k0 + sj * 8;
      pa[i][0] = *(const float4*)xa; pa[i][1] = *(const float4*)(xa + 4);
      pb[i][0] = *(const float4*)wa; pb[i][1] = *(const float4*)(wa + 4);
    }
  };
  auto pack8 = [](float4 a, float4 b) -> bf16x8 {
    bf16x8 v;
    v[0] = (bf16_t)a.x; v[1] = (bf16_t)a.y; v[2] = (bf16_t)a.z; v[3] = (bf16_t)a.w;
    v[4] = (bf16_t)b.x; v[5] = (bf16_t)b.y; v[6] = (bf16_t)b.z; v[7] = (bf16_t)b.w;
    return v;
  };

  f32x4 acc[4][4] = {};
  prefetch(0);

  for (int it = 0; it < 8; ++it) {
    __syncthreads();
#pragma unroll
    for (int i = 0; i < 4; ++i) {
      *(bf16x8*)(&u.s.A[sb][sr + i * 32][sc]) = pack8(pa[i][0], pa[i][1]);
      *(bf16x8*)(&u.s.B[sb][sr + i * 32][sc]) = pack8(pb[i][0], pb[i][1]);
    }
    __syncthreads();
    if (it < 7) prefetch((it + 1) * 64);

    bf16x8 af[4][2], bf[4][2];
#pragma unroll
    for (int mt = 0; mt < 4; ++mt)
#pragma unroll
      for (int kk = 0; kk < 2; ++kk)
        af[mt][kk] = *(const bf16x8*)(&u.s.A[kk][wr * 64 + mt * 16 + l15][quad * 8]);
#pragma unroll
    for (int nt = 0; nt < 4; ++nt)
#pragma unroll
      for (int kk = 0; kk < 2; ++kk)
        bf[nt][kk] = *(const bf16x8*)(&u.s.B[kk][wc * 64 + nt * 16 + l15][quad * 8]);
#pragma unroll
    for (int kk = 0; kk < 2; ++kk)
#pragma unroll
      for (int mt = 0; mt < 4; ++mt)
#pragma unroll
        for (int nt = 0; nt < 4; ++nt)
          acc[mt][nt] = MFMA16(af[mt][kk], bf[nt][kk], acc[mt][nt]);
  }

  __syncthreads();  // staging LDS -> relayout buffer reuse

  // Stage 1: +bias, bf16, into LDS (K: row-major [n][feat]; V: [feat][n]).
#pragma unroll
  for (int mt = 0; mt < 4; ++mt) {
#pragma unroll
    for (int nt = 0; nt < 4; ++nt) {
      const int F = wc * 64 + nt * 16 + l15;       // local feature 0..127
      const int c = n0 + F;                        // stacked feature 0..1023
      const float bb = zz ? bv[c - 512] : bk[c];
#pragma unroll
      for (int reg = 0; reg < 4; ++reg) {
        const int R = wr * 64 + mt * 16 + quad * 4 + reg;  // local row 0..127
        const float v = acc[mt][nt][reg] + bb;
        if (!zz) u.T[R][F] = (bf16_t)v;
        else     u.T[F][R] = (bf16_t)v;
      }
    }
  }
  __syncthreads();

  // Stage 2: fragment-major coalesced stores (1 KB per wave-store).
  if (!zz) {
    // 32 frags: hL(2) x kk(2) x ktl(8)
#pragma unroll
    for (int i = 0; i < 8; ++i) {
      const int fi  = i * 4 + w;
      const int hL  = fi >> 4, kk = (fi >> 3) & 1, ktl = fi & 7;
      const bf16x8 v = *(const bf16x8*)(&u.T[ktl * 16 + l15][hL * 64 + kk * 32 + quad * 8]);
      const int gr = m0 + ktl * 16 + l15;          // global key row
      const int b = gr >> 11, n = gr & (NSEQ - 1);
      const int bh = b * HEADS + (n0 >> 6) + hL;
      bf16_t* dst = Kf + (((size_t)(bh * 128 + (n >> 4)) * 2 + kk)) * 512 + lane * 8;
      *(bf16x8*)dst = v;
    }
  } else {
    // 32 frags: hL(2) x dt(4) x k32l(4)
#pragma unroll
    for (int i = 0; i < 8; ++i) {
      const int fi   = i * 4 + w;
      const int hL   = fi >> 4, dt = (fi >> 2) & 3, k32l = fi & 3;
      const bf16x8 v = *(const bf16x8*)(&u.T[hL * 64 + dt * 16 + l15][k32l * 32 + quad * 8]);
      const int gr = m0 + k32l * 32;               // key base (same b for block)
      const int b = gr >> 11, n = gr & (NSEQ - 1);
      const int bh = b * HEADS + ((n0 - 512) >> 6) + hL;
      bf16_t* dst = Vf + (((size_t)(bh * 64 + (n >> 5)) * 4 + dt)) * 512 + lane * 8;
      *(bf16x8*)dst = v;
    }
  }
}

// ---------------------------------------------------------------------------
// Flash attention, Q = K, fixed max m_i = ||k_i||^2 (validated R2-R6),
// S^T trick (validated R4-R6). R7: NO LDS staging, NO main-loop barriers.
// K/V/Q fragments loaded straight from global in fragment-major layout
// (coalesced dwordx4, L2-resident); kf register-double-buffered one iter
// ahead. Only per-wave-private P relayout uses LDS. l computed by MFMA
// row-sum (P x ones-frag) -> lands in C-layout, zero shuffles.
// Wave = 64 q-rows x 32 keys; 2x2 split (row-half x key-half); one barrier
// pair at the split-K combine. Grid (32 bh, 16) = 512 blocks.
// ---------------------------------------------------------------------------
__global__ __launch_bounds__(256, 2) void flash_kernel(
    const bf16_t* __restrict__ Kf, const bf16_t* __restrict__ Vf,
    float* __restrict__ out)
{
  __shared__ union {
    __align__(16) bf16_t Pl[4][64][40];      // per-wave P [qrow][32 keys + pad]
    struct {
      __align__(16) float Cb[2][4096];       // key-half-1 O partials
      __align__(16) float Lb[2][64][16];     // key-half-1 l partials
    } c;
  } u;

  const int t    = threadIdx.x;
  const int w    = t >> 6;
  const int lane = t & 63;
  const int quad = lane >> 4;
  const int l15  = lane & 15;
  const int rh   = w & 1;              // row-half
  const int kh   = w >> 1;             // key-half

  const int bh = blockIdx.x;           // 0..31 (id%8 = bh%8 -> XCD locality)
  const int b  = bh >> 3, h = bh & 7;
  const int rowbase = blockIdx.y * 128 + rh * 64;
  const int qtile   = rowbase >> 4;    // 16-row tile base 0..124

  const bf16_t* __restrict__ Kb = Kf + (size_t)bh * 128 * 2 * 512;
  const bf16_t* __restrict__ Vb = Vf + (size_t)bh * 64 * 4 * 512;

  // Resident Q fragments (coalesced frag loads; B-operand of S^T).
  bf16x8 qf[4][2];
#pragma unroll
  for (int nt = 0; nt < 4; ++nt)
#pragma unroll
    for (int kk = 0; kk < 2; ++kk)
      qf[nt][kk] = *(const bf16x8*)(Kb + ((size_t)(qtile + nt) * 2 + kk) * 512 + lane * 8);

  // Fixed max m_i = ||k_i||^2; lane's q-row for tile nt is nt*16+l15.
  float mlog[4];
#pragma unroll
  for (int nt = 0; nt < 4; ++nt) {
    float ss = 0.f;
#pragma unroll
    for (int kk = 0; kk < 2; ++kk)
#pragma unroll
      for (int j = 0; j < 8; ++j) {
        const float qv = (float)qf[nt][kk][j];
        ss = fmaf(qv, qv, ss);
      }
    ss += __shfl_xor(ss, 16, 64);
    ss += __shfl_xor(ss, 32, 64);
    mlog[nt] = ss * LOG2E;
  }

  bf16x8 ones;
#pragma unroll
  for (int j = 0; j < 8; ++j) ones[j] = (bf16_t)1.0f;

  // kf double-buffer: keys kt*64 + kh*32 .. +31 = 16-key tiles kt*4+kh*2+{0,1}
  bf16x8 kfb[2][2][2];
  auto load_k = [&](int kt, int buf) {
    const int kb = kt * 4 + kh * 2;
#pragma unroll
    for (int jt = 0; jt < 2; ++jt)
#pragma unroll
      for (int kk = 0; kk < 2; ++kk)
        kfb[buf][jt][kk] =
            *(const bf16x8*)(Kb + ((size_t)(kb + jt) * 2 + kk) * 512 + lane * 8);
  };

  f32x4 acco[4][4] = {};   // [row-tile][d-tile]
  f32x4 accll[4]   = {};   // l partials via ones-MFMA (C-layout)

  load_k(0, 0);

  for (int kt = 0; kt < NSEQ / 64; ++kt) {
    const int cur = kt & 1;

    // V frags for current tile (consumed ~500 cyc later in PV).
    bf16x8 vf[4];
    const int v32 = kt * 2 + kh;
#pragma unroll
    for (int dt = 0; dt < 4; ++dt)
      vf[dt] = *(const bf16x8*)(Vb + ((size_t)v32 * 4 + dt) * 512 + lane * 8);

    // S^T = K . Q^T (kf resident from previous iteration's prefetch).
    f32x4 st[2][4] = {};
#pragma unroll
    for (int kk = 0; kk < 2; ++kk)
#pragma unroll
      for (int jt = 0; jt < 2; ++jt)
#pragma unroll
        for (int nt = 0; nt < 4; ++nt)
          st[jt][nt] = MFMA16(kfb[cur][jt][kk], qf[nt][kk], st[jt][nt]);

    // Prefetch next K tile into the other buffer.
    const int ktn = (kt + 1 < NSEQ / 64) ? kt + 1 : kt;
    load_k(ktn, cur ^ 1);

    // P = exp(S - m); b64 scatter to per-wave LDS (C->A relayout).
#pragma unroll
    for (int jt = 0; jt < 2; ++jt)
#pragma unroll
      for (int nt = 0; nt < 4; ++nt) {
        union { bf16_t hx[4]; uint2 u2; } pw;
#pragma unroll
        for (int reg = 0; reg < 4; ++reg) {
          const float p =
              __builtin_amdgcn_exp2f(fmaf(st[jt][nt][reg], LOG2E, -mlog[nt]));
          pw.hx[reg] = (bf16_t)p;
        }
        *(uint2*)(&u.Pl[w][nt * 16 + l15][jt * 16 + quad * 4]) = pw.u2;
      }

    // P back in A-layout; O += P V, l += P . 1 (row-sum via ones-frag).
    bf16x8 pf[4];
#pragma unroll
    for (int rt = 0; rt < 4; ++rt)
      pf[rt] = *(const bf16x8*)(&u.Pl[w][rt * 16 + l15][quad * 8]);
#pragma unroll
    for (int rt = 0; rt < 4; ++rt) {
      accll[rt] = MFMA16(pf[rt], ones, accll[rt]);
#pragma unroll
      for (int dt = 0; dt < 4; ++dt)
        acco[rt][dt] = MFMA16(pf[rt], vf[dt], acco[rt][dt]);
    }
  }

  // Split-K combine: key-half-1 waves dump partials; key-half-0 waves add.
  __syncthreads();
  if (kh == 1) {
#pragma unroll
    for (int rt = 0; rt < 4; ++rt) {
#pragma unroll
      for (int dt = 0; dt < 4; ++dt)
        *(f32x4*)(&u.c.Cb[rh][((rt * 4 + dt) * 64 + lane) * 4]) = acco[rt][dt];
      *(f32x4*)(&u.c.Lb[rh][lane][rt * 4]) = accll[rt];
    }
  }
  __syncthreads();
  if (kh == 0) {
#pragma unroll
    for (int rt = 0; rt < 4; ++rt) {
#pragma unroll
      for (int dt = 0; dt < 4; ++dt)
        acco[rt][dt] += *(const f32x4*)(&u.c.Cb[rh][((rt * 4 + dt) * 64 + lane) * 4]);
      accll[rt] += *(const f32x4*)(&u.c.Lb[rh][lane][rt * 4]);
    }

    const float SCL = 0.044194173824159216f;  // 1/sqrt(512)
    // C-layout: accll[rt][reg] = l of q-row rt*16+quad*4+reg (any l15). No
    // shuffles needed — it is already aligned with acco's row mapping.
#pragma unroll
    for (int rt = 0; rt < 4; ++rt)
#pragma unroll
      for (int reg = 0; reg < 4; ++reg) {
        const float f = SCL / accll[rt][reg];
        const int n = rowbase + rt * 16 + quad * 4 + reg;
#pragma unroll
        for (int dt = 0; dt < 4; ++dt)
          out[((size_t)(b * NSEQ + n)) * EMB + h * HD + dt * 16 + l15] =
              acco[rt][dt][reg] * f;
      }
  }
}

extern "C" void kernel_launch(void* const* d_in, const int* in_sizes, int n_in,
                              void* d_out, int out_size, void* d_ws, size_t ws_size,
                              hipStream_t stream) {
  const float* x  = (const float*)d_in[0];
  const float* Wk = (const float*)d_in[1];
  const float* bk = (const float*)d_in[2];
  const float* Wv = (const float*)d_in[3];
  const float* bv = (const float*)d_in[4];
  float* out = (float*)d_out;

  bf16_t* Kf = (bf16_t*)d_ws;                                   // 8 MB
  bf16_t* Vf = Kf + (size_t)BATCH * HEADS * NSEQ * HD;          // 8 MB

  dim3 pg(8192 / 128, 1024 / 128);
  proj_kernel<<<pg, 256, 0, stream>>>(x, Wk, bk, Wv, bv, Kf, Vf);

  dim3 fg(BATCH * HEADS, NSEQ / 128);
  flash_kernel<<<fg, 256, 0, stream>>>(Kf, Vf, out);
}

// Round 8
// 128.576 us; speedup vs baseline: 14.7805x; 14.7805x over previous
//
#include <hip/hip_runtime.h>

typedef __bf16 bf16_t;
typedef bf16_t bf16x8 __attribute__((ext_vector_type(8)));
typedef float f32x4 __attribute__((ext_vector_type(4)));

#define NSEQ 2048
#define EMB 512
#define HEADS 8
#define HD 64
#define BATCH 4
#define LOG2E 1.4426950408889634f

#define MFMA16(a, b, c) __builtin_amdgcn_mfma_f32_16x16x32_bf16(a, b, c, 0, 0, 0)

// Fragment-major layouts (frag = 64 lanes x 8 bf16, contiguous 1 KB):
//   Kf[((bh*128 + kt16)*2 + kk)*512 + lane*8 + j]
//       = K[bh][key = kt16*16 + (lane&15)][d = kk*32 + (lane>>4)*8 + j]
//   Vf[((bh*64 + kt32)*4 + dt)*512 + lane*8 + j]
//       = V[bh][key = kt32*32 + (lane>>4)*8 + j][d = dt*16 + (lane&15)]

// ---------------------------------------------------------------------------
// Fused K/V projection GEMM with inline fp32->bf16 convert (R4-validated
// core): C[8192,1024] = x @ [Wk;Wv]^T + [bk;bv]. 128x128 tile, BK=64,
// register-prefetch pipeline. Epilogue emits FRAGMENT-MAJOR Kf/Vf.
// (unchanged from R7)
// ---------------------------------------------------------------------------
__global__ __launch_bounds__(256, 2) void proj_kernel(
    const float* __restrict__ x,
    const float* __restrict__ Wk, const float* __restrict__ bk,
    const float* __restrict__ Wv, const float* __restrict__ bv,
    bf16_t* __restrict__ Kf, bf16_t* __restrict__ Vf)
{
  __shared__ union {
    struct {
      __align__(16) bf16_t A[2][128][40];   // [kk-half][row][32 el + pad]
      __align__(16) bf16_t B[2][128][40];
    } s;
    __align__(16) bf16_t T[128][136];       // epilogue relayout buffer
  } u;

  const int t    = threadIdx.x;
  const int w    = t >> 6;
  const int lane = t & 63;
  const int quad = lane >> 4;
  const int l15  = lane & 15;
  const int wr   = w >> 1, wc = w & 1;
  const int m0   = blockIdx.x * 128;
  const int n0   = blockIdx.y * 128;        // stacked feature base 0..896
  const int zz   = (blockIdx.y >= 4);       // 0: K-features, 1: V-features
  const float* __restrict__ W = zz ? Wv : Wk;
  const int nW = n0 - zz * 512;             // row base within W

  const int sr = t >> 3;        // staging row 0..31 (x4 groups)
  const int sj = t & 7;         // 8-el chunk 0..7 within 64-el k slab
  const int sb = sj >> 2, sc = (sj & 3) * 8;

  float4 pa[4][2], pb[4][2];
  auto prefetch = [&](int k0) {
#pragma unroll
    for (int i = 0; i < 4; ++i) {
      const float* xa = x + (size_t)(m0 + sr + i * 32) * EMB + k0 + sj * 8;
      const float* wa = W + (size_t)(nW + sr + i * 32) * EMB + k0 + sj * 8;
      pa[i][0] = *(const float4*)xa; pa[i][1] = *(const float4*)(xa + 4);
      pb[i][0] = *(const float4*)wa; pb[i][1] = *(const float4*)(wa + 4);
    }
  };
  auto pack8 = [](float4 a, float4 b) -> bf16x8 {
    bf16x8 v;
    v[0] = (bf16_t)a.x; v[1] = (bf16_t)a.y; v[2] = (bf16_t)a.z; v[3] = (bf16_t)a.w;
    v[4] = (bf16_t)b.x; v[5] = (bf16_t)b.y; v[6] = (bf16_t)b.z; v[7] = (bf16_t)b.w;
    return v;
  };

  f32x4 acc[4][4] = {};
  prefetch(0);

  for (int it = 0; it < 8; ++it) {
    __syncthreads();
#pragma unroll
    for (int i = 0; i < 4; ++i) {
      *(bf16x8*)(&u.s.A[sb][sr + i * 32][sc]) = pack8(pa[i][0], pa[i][1]);
      *(bf16x8*)(&u.s.B[sb][sr + i * 32][sc]) = pack8(pb[i][0], pb[i][1]);
    }
    __syncthreads();
    if (it < 7) prefetch((it + 1) * 64);

    bf16x8 af[4][2], bf[4][2];
#pragma unroll
    for (int mt = 0; mt < 4; ++mt)
#pragma unroll
      for (int kk = 0; kk < 2; ++kk)
        af[mt][kk] = *(const bf16x8*)(&u.s.A[kk][wr * 64 + mt * 16 + l15][quad * 8]);
#pragma unroll
    for (int nt = 0; nt < 4; ++nt)
#pragma unroll
      for (int kk = 0; kk < 2; ++kk)
        bf[nt][kk] = *(const bf16x8*)(&u.s.B[kk][wc * 64 + nt * 16 + l15][quad * 8]);
#pragma unroll
    for (int kk = 0; kk < 2; ++kk)
#pragma unroll
      for (int mt = 0; mt < 4; ++mt)
#pragma unroll
        for (int nt = 0; nt < 4; ++nt)
          acc[mt][nt] = MFMA16(af[mt][kk], bf[nt][kk], acc[mt][nt]);
  }

  __syncthreads();  // staging LDS -> relayout buffer reuse

  // Stage 1: +bias, bf16, into LDS (K: row-major [n][feat]; V: [feat][n]).
#pragma unroll
  for (int mt = 0; mt < 4; ++mt) {
#pragma unroll
    for (int nt = 0; nt < 4; ++nt) {
      const int F = wc * 64 + nt * 16 + l15;       // local feature 0..127
      const int c = n0 + F;                        // stacked feature 0..1023
      const float bb = zz ? bv[c - 512] : bk[c];
#pragma unroll
      for (int reg = 0; reg < 4; ++reg) {
        const int R = wr * 64 + mt * 16 + quad * 4 + reg;  // local row 0..127
        const float v = acc[mt][nt][reg] + bb;
        if (!zz) u.T[R][F] = (bf16_t)v;
        else     u.T[F][R] = (bf16_t)v;
      }
    }
  }
  __syncthreads();

  // Stage 2: fragment-major coalesced stores (1 KB per wave-store).
  if (!zz) {
    // 32 frags: hL(2) x kk(2) x ktl(8)
#pragma unroll
    for (int i = 0; i < 8; ++i) {
      const int fi  = i * 4 + w;
      const int hL  = fi >> 4, kk = (fi >> 3) & 1, ktl = fi & 7;
      const bf16x8 v = *(const bf16x8*)(&u.T[ktl * 16 + l15][hL * 64 + kk * 32 + quad * 8]);
      const int gr = m0 + ktl * 16 + l15;          // global key row
      const int b = gr >> 11, n = gr & (NSEQ - 1);
      const int bh = b * HEADS + (n0 >> 6) + hL;
      bf16_t* dst = Kf + (((size_t)(bh * 128 + (n >> 4)) * 2 + kk)) * 512 + lane * 8;
      *(bf16x8*)dst = v;
    }
  } else {
    // 32 frags: hL(2) x dt(4) x k32l(4)
#pragma unroll
    for (int i = 0; i < 8; ++i) {
      const int fi   = i * 4 + w;
      const int hL   = fi >> 4, dt = (fi >> 2) & 3, k32l = fi & 3;
      const bf16x8 v = *(const bf16x8*)(&u.T[hL * 64 + dt * 16 + l15][k32l * 32 + quad * 8]);
      const int gr = m0 + k32l * 32;               // key base (same b for block)
      const int b = gr >> 11, n = gr & (NSEQ - 1);
      const int bh = b * HEADS + ((n0 - 512) >> 6) + hL;
      bf16_t* dst = Vf + (((size_t)(bh * 64 + (n >> 5)) * 4 + dt)) * 512 + lane * 8;
      *(bf16x8*)dst = v;
    }
  }
}

// ---------------------------------------------------------------------------
// Flash attention, Q = K, fixed max m_i = ||k_i||^2, S^T trick.
// R8 = R7's design with the register double-buffer SPILL-FREE: the K-loop is
// manually unrolled x2 with two statically-named buffers (kA, kB) so every
// register-array index is a compile-time constant (R7's kfb[cur] dynamic
// indexing forced scratch spills -> 36x slowdown).
// No LDS staging, no main-loop barriers; coalesced fragment-major global
// loads (L2-resident); P relayout via per-wave LDS; l via ones-MFMA.
// ---------------------------------------------------------------------------
__global__ __launch_bounds__(256, 2) void flash_kernel(
    const bf16_t* __restrict__ Kf, const bf16_t* __restrict__ Vf,
    float* __restrict__ out)
{
  __shared__ union {
    __align__(16) bf16_t Pl[4][64][40];      // per-wave P [qrow][32 keys + pad]
    struct {
      __align__(16) float Cb[2][4096];       // key-half-1 O partials
      __align__(16) float Lb[2][64][16];     // key-half-1 l partials
    } c;
  } u;

  const int t    = threadIdx.x;
  const int w    = t >> 6;
  const int lane = t & 63;
  const int quad = lane >> 4;
  const int l15  = lane & 15;
  const int rh   = w & 1;              // row-half
  const int kh   = w >> 1;             // key-half

  const int bh = blockIdx.x;           // 0..31 (id%8 = bh%8 -> XCD locality)
  const int b  = bh >> 3, h = bh & 7;
  const int rowbase = blockIdx.y * 128 + rh * 64;
  const int qtile   = rowbase >> 4;    // 16-row tile base 0..124

  const bf16_t* __restrict__ Kb = Kf + (size_t)bh * 128 * 2 * 512;
  const bf16_t* __restrict__ Vb = Vf + (size_t)bh * 64 * 4 * 512;

  // Resident Q fragments (coalesced frag loads; B-operand of S^T).
  bf16x8 qf[4][2];
#pragma unroll
  for (int nt = 0; nt < 4; ++nt)
#pragma unroll
    for (int kk = 0; kk < 2; ++kk)
      qf[nt][kk] = *(const bf16x8*)(Kb + ((size_t)(qtile + nt) * 2 + kk) * 512 + lane * 8);

  // Fixed max m_i = ||k_i||^2; lane's q-row for tile nt is nt*16+l15.
  float mlog[4];
#pragma unroll
  for (int nt = 0; nt < 4; ++nt) {
    float ss = 0.f;
#pragma unroll
    for (int kk = 0; kk < 2; ++kk)
#pragma unroll
      for (int j = 0; j < 8; ++j) {
        const float qv = (float)qf[nt][kk][j];
        ss = fmaf(qv, qv, ss);
      }
    ss += __shfl_xor(ss, 16, 64);
    ss += __shfl_xor(ss, 32, 64);
    mlog[nt] = ss * LOG2E;
  }

  bf16x8 ones;
#pragma unroll
  for (int j = 0; j < 8; ++j) ones[j] = (bf16_t)1.0f;

  f32x4 acco[4][4] = {};   // [row-tile][d-tile]
  f32x4 accll[4]   = {};   // l partials via ones-MFMA (C-layout)

  // K frag loader: keys kt*64 + kh*32 .. +31 = 16-key tiles kt*4+kh*2+{0,1}
  auto load_k = [&](int kt, bf16x8 (&dst)[2][2]) {
    const int kb = kt * 4 + kh * 2;
#pragma unroll
    for (int jt = 0; jt < 2; ++jt)
#pragma unroll
      for (int kk = 0; kk < 2; ++kk)
        dst[jt][kk] =
            *(const bf16x8*)(Kb + ((size_t)(kb + jt) * 2 + kk) * 512 + lane * 8);
  };

  // One tile: uses kcur (resident), prefetches kt+1 into knxt.
  auto body = [&](int kt, bf16x8 (&kcur)[2][2], bf16x8 (&knxt)[2][2]) {
    // V frags for current tile (consumed after S-phase).
    bf16x8 vf[4];
    const int v32 = kt * 2 + kh;
#pragma unroll
    for (int dt = 0; dt < 4; ++dt)
      vf[dt] = *(const bf16x8*)(Vb + ((size_t)v32 * 4 + dt) * 512 + lane * 8);

    // S^T = K . Q^T.
    f32x4 st[2][4] = {};
#pragma unroll
    for (int kk = 0; kk < 2; ++kk)
#pragma unroll
      for (int jt = 0; jt < 2; ++jt)
#pragma unroll
        for (int nt = 0; nt < 4; ++nt)
          st[jt][nt] = MFMA16(kcur[jt][kk], qf[nt][kk], st[jt][nt]);

    // Prefetch next K tile (clamped on last iter).
    load_k(kt + 1 < NSEQ / 64 ? kt + 1 : kt, knxt);

    // P = exp(S - m); b64 scatter to per-wave LDS (C->A relayout).
#pragma unroll
    for (int jt = 0; jt < 2; ++jt)
#pragma unroll
      for (int nt = 0; nt < 4; ++nt) {
        union { bf16_t hx[4]; uint2 u2; } pw;
#pragma unroll
        for (int reg = 0; reg < 4; ++reg) {
          const float p =
              __builtin_amdgcn_exp2f(fmaf(st[jt][nt][reg], LOG2E, -mlog[nt]));
          pw.hx[reg] = (bf16_t)p;
        }
        *(uint2*)(&u.Pl[w][nt * 16 + l15][jt * 16 + quad * 4]) = pw.u2;
      }

    // P back in A-layout; O += P V, l += P . 1.
    bf16x8 pf[4];
#pragma unroll
    for (int rt = 0; rt < 4; ++rt)
      pf[rt] = *(const bf16x8*)(&u.Pl[w][rt * 16 + l15][quad * 8]);
#pragma unroll
    for (int rt = 0; rt < 4; ++rt) {
      accll[rt] = MFMA16(pf[rt], ones, accll[rt]);
#pragma unroll
      for (int dt = 0; dt < 4; ++dt)
        acco[rt][dt] = MFMA16(pf[rt], vf[dt], acco[rt][dt]);
    }
  };

  bf16x8 kA[2][2], kB[2][2];
  load_k(0, kA);
  for (int kt = 0; kt < NSEQ / 64; kt += 2) {
    body(kt,     kA, kB);   // static buffer names -> no dynamic reg indexing
    body(kt + 1, kB, kA);
  }

  // Split-K combine: key-half-1 waves dump partials; key-half-0 waves add.
  __syncthreads();
  if (kh == 1) {
#pragma unroll
    for (int rt = 0; rt < 4; ++rt) {
#pragma unroll
      for (int dt = 0; dt < 4; ++dt)
        *(f32x4*)(&u.c.Cb[rh][((rt * 4 + dt) * 64 + lane) * 4]) = acco[rt][dt];
      *(f32x4*)(&u.c.Lb[rh][lane][rt * 4]) = accll[rt];
    }
  }
  __syncthreads();
  if (kh == 0) {
#pragma unroll
    for (int rt = 0; rt < 4; ++rt) {
#pragma unroll
      for (int dt = 0; dt < 4; ++dt)
        acco[rt][dt] += *(const f32x4*)(&u.c.Cb[rh][((rt * 4 + dt) * 64 + lane) * 4]);
      accll[rt] += *(const f32x4*)(&u.c.Lb[rh][lane][rt * 4]);
    }

    const float SCL = 0.044194173824159216f;  // 1/sqrt(512)
    // accll[rt][reg] = l of q-row rt*16+quad*4+reg — already acco-aligned.
#pragma unroll
    for (int rt = 0; rt < 4; ++rt)
#pragma unroll
      for (int reg = 0; reg < 4; ++reg) {
        const float f = SCL / accll[rt][reg];
        const int n = rowbase + rt * 16 + quad * 4 + reg;
#pragma unroll
        for (int dt = 0; dt < 4; ++dt)
          out[((size_t)(b * NSEQ + n)) * EMB + h * HD + dt * 16 + l15] =
              acco[rt][dt][reg] * f;
      }
  }
}

extern "C" void kernel_launch(void* const* d_in, const int* in_sizes, int n_in,
                              void* d_out, int out_size, void* d_ws, size_t ws_size,
                              hipStream_t stream) {
  const float* x  = (const float*)d_in[0];
  const float* Wk = (const float*)d_in[1];
  const float* bk = (const float*)d_in[2];
  const float* Wv = (const float*)d_in[3];
  const float* bv = (const float*)d_in[4];
  float* out = (float*)d_out;

  bf16_t* Kf = (bf16_t*)d_ws;                                   // 8 MB
  bf16_t* Vf = Kf + (size_t)BATCH * HEADS * NSEQ * HD;          // 8 MB

  dim3 pg(8192 / 128, 1024 / 128);
  proj_kernel<<<pg, 256, 0, stream>>>(x, Wk, bk, Wv, bv, Kf, Vf);

  dim3 fg(BATCH * HEADS, NSEQ / 128);
  flash_kernel<<<fg, 256, 0, stream>>>(Kf, Vf, out);
}